// Round 1
// baseline (5636.756 us; speedup 1.0000x reference)
//
#include <hip/hip_runtime.h>
#include <hip/hip_bf16.h>
#include <math.h>

#define BT 2
#define SL 2048
#define HIDN 2048
#define NHEADS 16
#define DNOPE 128
#define DROPE 64
#define DVAL 128
#define QHEAD 192
#define QLRANK 1536
#define KVLRANK 512
#define TTOK (BT * SL)

// ---------------- generic f32 GEMM: C[M,N] = A[M,K] @ B[K,N], row-major ----------------
// tile: BM=128, BN=64, BK=16; 256 threads; 8x4 micro-tile per thread.
template <int EPI>  // 0 = none, 1 = sigmoid
__global__ __launch_bounds__(256) void gemm_f32_k(const float* __restrict__ A,
                                                  const float* __restrict__ B,
                                                  float* __restrict__ C, int M, int N, int K) {
    __shared__ float As[16][136];  // [k][m] (transposed), pad 136
    __shared__ float Bs[16][68];   // [k][n], pad 68
    const int t = threadIdx.x;
    const int tx = t & 15, ty = t >> 4;
    const int bn = blockIdx.x * 64;
    const int bm = blockIdx.y * 128;
    // staging maps
    const int arow = t >> 2, ak4 = (t & 3) * 4;  // A: 2 rows per thread (arow, arow+64), 4 k's
    const int bkk = t >> 4, bc4 = (t & 15) * 4;  // B: 1 float4 per thread
    const float* Ag0 = A + (bm + arow) * K + ak4;
    const float* Ag1 = Ag0 + 64 * K;
    const float* Bg = B + bkk * N + bn + bc4;

    float acc[8][4];
#pragma unroll
    for (int i = 0; i < 8; ++i)
#pragma unroll
        for (int j = 0; j < 4; ++j) acc[i][j] = 0.f;

    for (int k0 = 0; k0 < K; k0 += 16) {
        const float4 av0 = *(const float4*)(Ag0 + k0);
        const float4 av1 = *(const float4*)(Ag1 + k0);
        const float4 bv = *(const float4*)(Bg + k0 * N);
        __syncthreads();  // protect previous iteration's LDS reads
        As[ak4 + 0][arow] = av0.x;
        As[ak4 + 1][arow] = av0.y;
        As[ak4 + 2][arow] = av0.z;
        As[ak4 + 3][arow] = av0.w;
        As[ak4 + 0][arow + 64] = av1.x;
        As[ak4 + 1][arow + 64] = av1.y;
        As[ak4 + 2][arow + 64] = av1.z;
        As[ak4 + 3][arow + 64] = av1.w;
        *(float4*)&Bs[bkk][bc4] = bv;
        __syncthreads();
#pragma unroll
        for (int kk = 0; kk < 16; ++kk) {
            const float4 a0 = *(const float4*)&As[kk][ty * 8];
            const float4 a1 = *(const float4*)&As[kk][ty * 8 + 4];
            const float4 b0 = *(const float4*)&Bs[kk][tx * 4];
            const float ar[8] = {a0.x, a0.y, a0.z, a0.w, a1.x, a1.y, a1.z, a1.w};
            const float br[4] = {b0.x, b0.y, b0.z, b0.w};
#pragma unroll
            for (int i = 0; i < 8; ++i)
#pragma unroll
                for (int j = 0; j < 4; ++j) acc[i][j] = fmaf(ar[i], br[j], acc[i][j]);
        }
    }
    const int row0 = bm + ty * 8, col0 = bn + tx * 4;
#pragma unroll
    for (int i = 0; i < 8; ++i) {
        float4 v;
        v.x = acc[i][0];
        v.y = acc[i][1];
        v.z = acc[i][2];
        v.w = acc[i][3];
        if (EPI == 1) {
            v.x = 1.f / (1.f + expf(-v.x));
            v.y = 1.f / (1.f + expf(-v.y));
            v.z = 1.f / (1.f + expf(-v.z));
            v.w = 1.f / (1.f + expf(-v.w));
        }
        *(float4*)&C[(row0 + i) * N + col0] = v;
    }
}

// ---------------- RMS norm over first nlen cols of each row ----------------
__global__ __launch_bounds__(256) void rmsnorm_k(const float* __restrict__ in,
                                                 float* __restrict__ out,
                                                 const float* __restrict__ w, int in_stride,
                                                 int out_stride, int nlen) {
    const int row = blockIdx.x;
    const int t = threadIdx.x;
    const float* x = in + row * in_stride;
    float* y = out + row * out_stride;
    float ss = 0.f;
    for (int d = t; d < nlen; d += 256) {
        float v = x[d];
        ss += v * v;
    }
    ss += __shfl_down(ss, 32);
    ss += __shfl_down(ss, 16);
    ss += __shfl_down(ss, 8);
    ss += __shfl_down(ss, 4);
    ss += __shfl_down(ss, 2);
    ss += __shfl_down(ss, 1);
    __shared__ float red[5];
    if ((t & 63) == 0) red[t >> 6] = ss;
    __syncthreads();
    if (t == 0) red[4] = rsqrtf((red[0] + red[1] + red[2] + red[3]) / (float)nlen + 1e-6f);
    __syncthreads();
    const float sc = red[4];
    for (int d = t; d < nlen; d += 256) y[d] = x[d] * sc * (1.f + w[d]);
}

// ---------------- RoPE: in-place on q (dims 128..191 per head), ckv rope part -> kr ----------------
__global__ __launch_bounds__(64) void rope_k(float* __restrict__ q, const float* __restrict__ ckv,
                                             float* __restrict__ kr,
                                             const int* __restrict__ pos_ids) {
    const int tok = blockIdx.x * 2 + (threadIdx.x >> 5);
    const int j = threadIdx.x & 31;
    const int s = tok & (SL - 1);
    const float pos = (float)pos_ids[s];
    const float inv = 1.f / powf(10000.f, (float)(2 * j) / 64.f);
    const float f = pos * inv;
    const float c = cosf(f), sn = sinf(f);
    // k_rope (shared across heads)
    const float* kc = ckv + tok * 576 + 512;
    const float ke = kc[2 * j], ko = kc[2 * j + 1];
    kr[tok * 64 + j] = ke * c - ko * sn;
    kr[tok * 64 + 32 + j] = ko * c + ke * sn;
    // q heads
#pragma unroll
    for (int h = 0; h < NHEADS; ++h) {
        float* qb = q + (tok * NHEADS + h) * QHEAD + DNOPE;
        const float qe = qb[2 * j], qo = qb[2 * j + 1];
        // all lanes' loads return before any store issues (same wave, data dep) -> in-place safe
        qb[j] = qe * c - qo * sn;
        qb[32 + j] = qo * c + qe * sn;
    }
}

// ---------------- flash attention (non-causal), gate fused in epilogue ----------------
// grid: 32 bh * 128 qtiles; block 256. BQ=16, BK=32.
__global__ __launch_bounds__(256) void mla_attn_k(const float* __restrict__ q,
                                                  const float* __restrict__ kv,
                                                  const float* __restrict__ kr,
                                                  const float* __restrict__ gate,
                                                  float* __restrict__ outg) {
    __shared__ float Qs[16][196];
    __shared__ float Ks[32][196];
    __shared__ float Vs[32][132];
    __shared__ float Sl[16][33];
    __shared__ float Pl[16][33];
    const int bh = blockIdx.x >> 7, qt = blockIdx.x & 127;
    const int b = bh >> 4, h = bh & 15;
    const int t = threadIdx.x;
    const int r = t & 15, g = t >> 4;
    const float scale = 0.07216878364870322f;  // 1/sqrt(192)
    const int q0 = qt * 16;

    // load Q tile (scaled)
    for (int idx = t; idx < 16 * 128; idx += 256) {
        const int rr = idx >> 7, d = idx & 127;
        Qs[rr][d] = q[((b * SL + q0 + rr) * NHEADS + h) * QHEAD + d] * scale;
    }
    for (int idx = t; idx < 16 * 64; idx += 256) {
        const int rr = idx >> 6, d = idx & 63;
        Qs[rr][128 + d] = q[((b * SL + q0 + rr) * NHEADS + h) * QHEAD + 128 + d] * scale;
    }

    float m = -INFINITY, l = 0.f;
    float O[8] = {0.f, 0.f, 0.f, 0.f, 0.f, 0.f, 0.f, 0.f};

    for (int k0 = 0; k0 < SL; k0 += 32) {
        __syncthreads();  // guard K/V/S/P overwrite vs prev-iter reads (also makes Q visible, iter 0)
        for (int idx = t; idx < 32 * 128; idx += 256) {
            const int c = idx >> 7, d = idx & 127;
            const int tok = b * SL + k0 + c;
            Ks[c][d] = kv[(tok * NHEADS + h) * 256 + d];
        }
        for (int idx = t; idx < 32 * 64; idx += 256) {
            const int c = idx >> 6, d = idx & 63;
            const int tok = b * SL + k0 + c;
            Ks[c][128 + d] = kr[tok * 64 + d];
        }
        for (int idx = t; idx < 32 * 128; idx += 256) {
            const int c = idx >> 7, d = idx & 127;
            const int tok = b * SL + k0 + c;
            Vs[c][d] = kv[(tok * NHEADS + h) * 256 + 128 + d];
        }
        __syncthreads();
        // scores for keys g and g+16
        float s0 = 0.f, s1 = 0.f;
#pragma unroll
        for (int d = 0; d < 192; d += 4) {
            const float4 qa = *(const float4*)&Qs[r][d];
            const float4 ka = *(const float4*)&Ks[g][d];
            const float4 kb = *(const float4*)&Ks[g + 16][d];
            s0 += qa.x * ka.x + qa.y * ka.y + qa.z * ka.z + qa.w * ka.w;
            s1 += qa.x * kb.x + qa.y * kb.y + qa.z * kb.z + qa.w * kb.w;
        }
        Sl[r][g] = s0;
        Sl[r][g + 16] = s1;
        __syncthreads();
        float mt = m;
#pragma unroll
        for (int c = 0; c < 32; ++c) mt = fmaxf(mt, Sl[r][c]);
        Pl[r][g] = expf(s0 - mt);
        Pl[r][g + 16] = expf(s1 - mt);
        __syncthreads();
        const float alpha = expf(m - mt);  // expf(-inf)=0 on first tile
        float ls = 0.f;
#pragma unroll
        for (int c = 0; c < 32; ++c) ls += Pl[r][c];
        l = l * alpha + ls;
        m = mt;
#pragma unroll
        for (int j = 0; j < 8; ++j) O[j] *= alpha;
#pragma unroll
        for (int c = 0; c < 32; ++c) {
            const float pc = Pl[r][c];
            const float4 v0 = *(const float4*)&Vs[c][g * 8];
            const float4 v1 = *(const float4*)&Vs[c][g * 8 + 4];
            O[0] = fmaf(pc, v0.x, O[0]);
            O[1] = fmaf(pc, v0.y, O[1]);
            O[2] = fmaf(pc, v0.z, O[2]);
            O[3] = fmaf(pc, v0.w, O[3]);
            O[4] = fmaf(pc, v1.x, O[4]);
            O[5] = fmaf(pc, v1.y, O[5]);
            O[6] = fmaf(pc, v1.z, O[6]);
            O[7] = fmaf(pc, v1.w, O[7]);
        }
    }
    // epilogue: /l, *sigmoid(gate) (gate buffer already sigmoided), write transposed layout
    const int tok = b * SL + q0 + r;
    const float invl = 1.f / l;
    const int base = tok * (NHEADS * DVAL) + h * DVAL + g * 8;
#pragma unroll
    for (int j = 0; j < 8; ++j) outg[base + j] = O[j] * invl * gate[base + j];
}

extern "C" void kernel_launch(void* const* d_in, const int* in_sizes, int n_in, void* d_out,
                              int out_size, void* d_ws, size_t ws_size, hipStream_t stream) {
    const float* hs = (const float*)d_in[0];
    const int* pos = (const int*)d_in[1];
    const float* Wq_down = (const float*)d_in[2];
    const float* q_norm_w = (const float*)d_in[3];
    const float* Wq_up = (const float*)d_in[4];
    const float* Wkv_down = (const float*)d_in[5];
    const float* kv_norm_w = (const float*)d_in[6];
    const float* Wkv_up = (const float*)d_in[7];
    const float* W_gate = (const float*)d_in[8];
    const float* W_out = (const float*)d_in[9];
    float* out = (float*)d_out;

    float* ws = (float*)d_ws;
    float* qdown = ws;                       // T*1536
    float* qbuf = qdown + TTOK * QLRANK;     // T*3072
    float* ckv = qbuf + TTOK * (NHEADS * QHEAD);  // T*576
    float* kvn = ckv + TTOK * 576;           // T*512
    float* kvbuf = kvn + TTOK * KVLRANK;     // T*4096
    float* kr = kvbuf + TTOK * (NHEADS * 256);  // T*64
    float* gateb = kr + TTOK * DROPE;        // T*2048
    float* outg = gateb + TTOK * (NHEADS * DVAL);  // T*2048

    const dim3 blk(256);

    // 1) q_down = hs @ Wq_down  [T,1536]
    gemm_f32_k<0><<<dim3(QLRANK / 64, TTOK / 128), blk, 0, stream>>>(hs, Wq_down, qdown, TTOK,
                                                                    QLRANK, HIDN);
    // 2) rms_norm(q_down) in-place
    rmsnorm_k<<<dim3(TTOK), blk, 0, stream>>>(qdown, qdown, q_norm_w, QLRANK, QLRANK, QLRANK);
    // 3) q = qn @ Wq_up  [T,3072]
    gemm_f32_k<0><<<dim3((NHEADS * QHEAD) / 64, TTOK / 128), blk, 0, stream>>>(
        qdown, Wq_up, qbuf, TTOK, NHEADS * QHEAD, QLRANK);
    // 4) ckv = hs @ Wkv_down  [T,576]
    gemm_f32_k<0><<<dim3(576 / 64, TTOK / 128), blk, 0, stream>>>(hs, Wkv_down, ckv, TTOK, 576,
                                                                  HIDN);
    // 5) kvn = rms_norm(ckv[:, :512])
    rmsnorm_k<<<dim3(TTOK), blk, 0, stream>>>(ckv, kvn, kv_norm_w, 576, KVLRANK, KVLRANK);
    // 6) kv = kvn @ Wkv_up  [T,4096]
    gemm_f32_k<0><<<dim3((NHEADS * 256) / 64, TTOK / 128), blk, 0, stream>>>(
        kvn, Wkv_up, kvbuf, TTOK, NHEADS * 256, KVLRANK);
    // 7) RoPE on q (in place) + k_rope -> kr
    rope_k<<<dim3(TTOK / 2), dim3(64), 0, stream>>>(qbuf, ckv, kr, pos);
    // 8) gate = sigmoid(hs @ W_gate)  [T,2048]
    gemm_f32_k<1><<<dim3((NHEADS * DVAL) / 64, TTOK / 128), blk, 0, stream>>>(hs, W_gate, gateb,
                                                                              TTOK, NHEADS * DVAL,
                                                                              HIDN);
    // 9) attention + gate multiply -> outg [T,2048] (b,q,h,d layout)
    mla_attn_k<<<dim3(32 * 128), blk, 0, stream>>>(qbuf, kvbuf, kr, gateb, outg);
    // 10) final = outg @ W_out -> d_out [T,2048]
    gemm_f32_k<0><<<dim3(HIDN / 64, TTOK / 128), blk, 0, stream>>>(outg, W_out, out, TTOK, HIDN,
                                                                   NHEADS * DVAL);
}

// Round 3
// 814.622 us; speedup vs baseline: 6.9195x; 6.9195x over previous
//
#include <hip/hip_runtime.h>
#include <math.h>

#define BT 2
#define SL 2048
#define HIDN 2048
#define NHEADS 16
#define DNOPE 128
#define DROPE 64
#define DVAL 128
#define QHEAD 192
#define QLRANK 1536
#define KVLRANK 512
#define TTOK (BT * SL)

typedef unsigned short u16;
typedef u16 u16x4 __attribute__((ext_vector_type(4)));
typedef short bf16x8 __attribute__((ext_vector_type(8)));
typedef float f32x4 __attribute__((ext_vector_type(4)));

__device__ __forceinline__ u16 f2b(float f) {
    union { float f; unsigned u; } v; v.f = f;
    unsigned r = v.u + 0x7FFFu + ((v.u >> 16) & 1u);
    return (u16)(r >> 16);
}
__device__ __forceinline__ float b2f(u16 h) {
    union { unsigned u; float f; } v; v.u = ((unsigned)h) << 16;
    return v.f;
}

// ---------------- cast f32 -> bf16 (vectorized) ----------------
__global__ __launch_bounds__(256) void cast_k(const float* __restrict__ in, u16* __restrict__ out,
                                              int n4) {
    int i = blockIdx.x * 256 + threadIdx.x;
    const int stride = gridDim.x * 256;
    for (; i < n4; i += stride) {
        const float4 v = ((const float4*)in)[i];
        u16x4 u;
        u.x = f2b(v.x); u.y = f2b(v.y); u.z = f2b(v.z); u.w = f2b(v.w);
        ((u16x4*)out)[i] = u;
    }
}

// ---------------- transpose-cast: in [R][C] f32 -> out [C][R] bf16, 64x64 LDS tiles ----------------
__global__ __launch_bounds__(256) void tcast_k(const float* __restrict__ in, u16* __restrict__ out,
                                               int R, int C) {
    __shared__ u16 tile[64][72];
    const int c0 = blockIdx.x * 64, r0 = blockIdx.y * 64;
    const int t = threadIdx.x;
    const int tr = t >> 4, tc4 = (t & 15) * 4;
#pragma unroll
    for (int i = 0; i < 4; ++i) {
        const int r = tr + i * 16;
        const float4 v = *(const float4*)&in[(r0 + r) * C + c0 + tc4];
        u16x4 u;
        u.x = f2b(v.x); u.y = f2b(v.y); u.z = f2b(v.z); u.w = f2b(v.w);
        *(u16x4*)&tile[r][tc4] = u;
    }
    __syncthreads();
#pragma unroll
    for (int i = 0; i < 4; ++i) {
        const int rr = tr + i * 16;  // output row = input col
        u16x4 u;
        u.x = tile[tc4 + 0][rr];
        u.y = tile[tc4 + 1][rr];
        u.z = tile[tc4 + 2][rr];
        u.w = tile[tc4 + 3][rr];
        *(u16x4*)&out[(c0 + rr) * R + r0 + tc4] = u;
    }
}

// ---------------- V transpose: kvbuf [tok][h*256+128+d] bf16 -> vT [bh][128][2048] bf16 ----------------
__global__ __launch_bounds__(256) void vtrans_k(const u16* __restrict__ kvbuf,
                                                u16* __restrict__ vT) {
    __shared__ u16 tile[64][72];
    const int bh = blockIdx.z;
    const int b = bh >> 4, h = bh & 15;
    const int s0 = blockIdx.x * 64, d0 = blockIdx.y * 64;
    const int t = threadIdx.x;
    const int tr = t >> 4, tc4 = (t & 15) * 4;
#pragma unroll
    for (int i = 0; i < 4; ++i) {
        const int s = tr + i * 16;
        *(u16x4*)&tile[s][tc4] =
            *(const u16x4*)&kvbuf[(b * SL + s0 + s) * 4096 + h * 256 + 128 + d0 + tc4];
    }
    __syncthreads();
#pragma unroll
    for (int i = 0; i < 4; ++i) {
        const int dd = tr + i * 16;
        u16x4 u;
        u.x = tile[tc4 + 0][dd];
        u.y = tile[tc4 + 1][dd];
        u.z = tile[tc4 + 2][dd];
        u.w = tile[tc4 + 3][dd];
        *(u16x4*)&vT[(bh * 128 + d0 + dd) * SL + s0 + tc4] = u;
    }
}

// ---------------- bf16 MFMA GEMM: C[M,N] = A[M,K] @ Bt[N,K]^T ----------------
// 128x128 tile, BK=64, 256 threads (4 waves 2x2), 4x4 16x16x32 frags per wave.
template <int EPI, int OUTF>  // EPI: 0 none, 1 sigmoid; OUTF: 0 bf16 out, 1 f32 out
__global__ __launch_bounds__(256) void gemm_bf16_k(const u16* __restrict__ A,
                                                   const u16* __restrict__ Bt,
                                                   void* __restrict__ Cv, int M, int N, int K) {
    __shared__ u16 As[128 * 72];
    __shared__ u16 Bs[128 * 72];
    const int t = threadIdx.x;
    const int bn = blockIdx.x * 128, bm = blockIdx.y * 128;
    const int w = t >> 6, lane = t & 63;
    const int wr = (w >> 1) * 64, wc = (w & 1) * 64;
    const int lr = lane & 15, lg = lane >> 4;
    const int srow = t >> 4, sc4 = (t & 15) * 4;

    f32x4 acc[4][4];
#pragma unroll
    for (int i = 0; i < 4; ++i)
#pragma unroll
        for (int j = 0; j < 4; ++j) acc[i][j] = 0.f;

    for (int k0 = 0; k0 < K; k0 += 64) {
        u16x4 av[8], bv[8];
#pragma unroll
        for (int i = 0; i < 8; ++i) {
            av[i] = *(const u16x4*)&A[(bm + srow + i * 16) * K + k0 + sc4];
            const int brow = bn + srow + i * 16;
            u16x4 z; z.x = 0; z.y = 0; z.z = 0; z.w = 0;
            bv[i] = (brow < N) ? *(const u16x4*)&Bt[brow * K + k0 + sc4] : z;
        }
        __syncthreads();  // protect previous iteration's LDS reads
#pragma unroll
        for (int i = 0; i < 8; ++i) {
            *(u16x4*)&As[(srow + i * 16) * 72 + sc4] = av[i];
            *(u16x4*)&Bs[(srow + i * 16) * 72 + sc4] = bv[i];
        }
        __syncthreads();
#pragma unroll
        for (int kk = 0; kk < 2; ++kk) {
            bf16x8 af[4], bfr[4];
#pragma unroll
            for (int mi = 0; mi < 4; ++mi)
                af[mi] = *(const bf16x8*)&As[(wr + mi * 16 + lr) * 72 + kk * 32 + lg * 8];
#pragma unroll
            for (int ni = 0; ni < 4; ++ni)
                bfr[ni] = *(const bf16x8*)&Bs[(wc + ni * 16 + lr) * 72 + kk * 32 + lg * 8];
#pragma unroll
            for (int mi = 0; mi < 4; ++mi)
#pragma unroll
                for (int ni = 0; ni < 4; ++ni)
                    acc[mi][ni] = __builtin_amdgcn_mfma_f32_16x16x32_bf16(af[mi], bfr[ni],
                                                                          acc[mi][ni], 0, 0, 0);
        }
    }
#pragma unroll
    for (int mi = 0; mi < 4; ++mi)
#pragma unroll
        for (int ni = 0; ni < 4; ++ni)
#pragma unroll
            for (int r = 0; r < 4; ++r) {
                const int row = bm + wr + mi * 16 + lg * 4 + r;
                const int col = bn + wc + ni * 16 + lr;
                float v = acc[mi][ni][r];
                if (EPI == 1) v = 1.f / (1.f + __expf(-v));
                if (col < N) {
                    if (OUTF)
                        ((float*)Cv)[row * N + col] = v;
                    else
                        ((u16*)Cv)[row * N + col] = f2b(v);
                }
            }
}

// ---------------- RMS norm (bf16 in/out, f32 weight) ----------------
__global__ __launch_bounds__(256) void rmsnorm_k(const u16* __restrict__ in, u16* __restrict__ out,
                                                 const float* __restrict__ w, int is, int os,
                                                 int n) {
    const int row = blockIdx.x;
    const int t = threadIdx.x;
    const u16* x = in + row * is;
    u16* y = out + row * os;
    float ss = 0.f;
    for (int d = t * 4; d < n; d += 1024) {
        const u16x4 u = *(const u16x4*)&x[d];
        const float a = b2f(u.x), b = b2f(u.y), c = b2f(u.z), e = b2f(u.w);
        ss += a * a + b * b + c * c + e * e;
    }
    ss += __shfl_down(ss, 32);
    ss += __shfl_down(ss, 16);
    ss += __shfl_down(ss, 8);
    ss += __shfl_down(ss, 4);
    ss += __shfl_down(ss, 2);
    ss += __shfl_down(ss, 1);
    __shared__ float red[5];
    if ((t & 63) == 0) red[t >> 6] = ss;
    __syncthreads();
    if (t == 0) red[4] = rsqrtf((red[0] + red[1] + red[2] + red[3]) / (float)n + 1e-6f);
    __syncthreads();
    const float sc = red[4];
    for (int d = t * 4; d < n; d += 1024) {
        const u16x4 u = *(const u16x4*)&x[d];
        const float4 wv = *(const float4*)&w[d];
        u16x4 o;
        o.x = f2b(b2f(u.x) * sc * (1.f + wv.x));
        o.y = f2b(b2f(u.y) * sc * (1.f + wv.y));
        o.z = f2b(b2f(u.z) * sc * (1.f + wv.z));
        o.w = f2b(b2f(u.w) * sc * (1.f + wv.w));
        *(u16x4*)&y[d] = o;
    }
}

// ---------------- RoPE (bf16): q in-place, ckv rope slice -> kr ----------------
__global__ __launch_bounds__(64) void rope_k(u16* __restrict__ q, const u16* __restrict__ ckv,
                                             u16* __restrict__ kr, const int* __restrict__ pos_ids) {
    const int tok = blockIdx.x * 2 + (threadIdx.x >> 5);
    const int j = threadIdx.x & 31;
    const int s = tok & (SL - 1);
    const float pos = (float)pos_ids[s];
    const float inv = 1.f / powf(10000.f, (float)(2 * j) / 64.f);
    const float f = pos * inv;
    const float c = cosf(f), sn = sinf(f);
    const u16* kc = ckv + tok * 576 + 512;
    const float ke = b2f(kc[2 * j]), ko = b2f(kc[2 * j + 1]);
    kr[tok * 64 + j] = f2b(ke * c - ko * sn);
    kr[tok * 64 + 32 + j] = f2b(ko * c + ke * sn);
#pragma unroll
    for (int h = 0; h < NHEADS; ++h) {
        u16* qb = q + tok * (NHEADS * QHEAD) + h * QHEAD + DNOPE;
        const float qe = b2f(qb[2 * j]), qo = b2f(qb[2 * j + 1]);
        qb[j] = f2b(qe * c - qo * sn);
        qb[32 + j] = f2b(qo * c + qe * sn);
    }
}

// ---------------- MFMA flash attention, gate fused ----------------
// block = 256 (4 waves); each block: one (b,h), 64 q-rows (16/wave); key tiles of 64.
__global__ __launch_bounds__(256) void mla_attn_k(const u16* __restrict__ qbuf,
                                                  const u16* __restrict__ kvbuf,
                                                  const u16* __restrict__ kr,
                                                  const u16* __restrict__ vT,
                                                  const u16* __restrict__ gateb,
                                                  u16* __restrict__ outg) {
    __shared__ u16 Ks[64 * 200];
    __shared__ u16 Vt[128 * 72];
    __shared__ u16 Ps[4 * 16 * 72];
    const int bh = blockIdx.y;
    const int b = bh >> 4, h = bh & 15;
    const int q0 = blockIdx.x * 64;
    const int t = threadIdx.x, w = t >> 6, lane = t & 63;
    const int lr = lane & 15, lg = lane >> 4;
    const float scale = 0.07216878364870322f;  // 1/sqrt(192)

    // Q fragments in registers: wave w owns q rows q0+w*16 .. +15
    bf16x8 aq[6];
    {
        const int qrow = b * SL + q0 + w * 16 + lr;
#pragma unroll
        for (int ks = 0; ks < 6; ++ks)
            aq[ks] = *(const bf16x8*)&qbuf[qrow * (NHEADS * QHEAD) + h * QHEAD + ks * 32 + lg * 8];
    }

    f32x4 O[8];
#pragma unroll
    for (int df = 0; df < 8; ++df) O[df] = 0.f;
    float m[4] = {-INFINITY, -INFINITY, -INFINITY, -INFINITY};
    float l[4] = {0.f, 0.f, 0.f, 0.f};

    for (int k0 = 0; k0 < SL; k0 += 64) {
        __syncthreads();  // prior iteration's reads done before overwrite
        // K tile: 64 rows x 192 cols = 3072 u16x4 chunks
        for (int i = t; i < 3072; i += 256) {
            const int row = i / 48, c4 = (i % 48) * 4;
            const int tok = b * SL + k0 + row;
            u16x4 v;
            if (c4 < 128)
                v = *(const u16x4*)&kvbuf[tok * 4096 + h * 256 + c4];
            else
                v = *(const u16x4*)&kr[tok * 64 + (c4 - 128)];
            *(u16x4*)&Ks[row * 200 + c4] = v;
        }
        for (int i = t; i < 2048; i += 256) {
            const int row = i >> 4, c4 = (i & 15) * 4;
            *(u16x4*)&Vt[row * 72 + c4] = *(const u16x4*)&vT[(bh * 128 + row) * SL + k0 + c4];
        }
        __syncthreads();

        // S = Q K^T  (4 n-frags of 16 keys, 6 k-steps over d=192)
        f32x4 s[4];
#pragma unroll
        for (int nf = 0; nf < 4; ++nf) s[nf] = 0.f;
#pragma unroll
        for (int ks = 0; ks < 6; ++ks) {
#pragma unroll
            for (int nf = 0; nf < 4; ++nf) {
                const bf16x8 bk = *(const bf16x8*)&Ks[(nf * 16 + lr) * 200 + ks * 32 + lg * 8];
                s[nf] = __builtin_amdgcn_mfma_f32_16x16x32_bf16(aq[ks], bk, s[nf], 0, 0, 0);
            }
        }
        // online softmax (rows: lg*4+r; cols: lr + 16*nf)
        float p[4][4];
#pragma unroll
        for (int r = 0; r < 4; ++r) {
            float sv[4];
            float lm = -INFINITY;
#pragma unroll
            for (int nf = 0; nf < 4; ++nf) {
                sv[nf] = s[nf][r] * scale;
                lm = fmaxf(lm, sv[nf]);
            }
            lm = fmaxf(lm, __shfl_xor(lm, 1));
            lm = fmaxf(lm, __shfl_xor(lm, 2));
            lm = fmaxf(lm, __shfl_xor(lm, 4));
            lm = fmaxf(lm, __shfl_xor(lm, 8));
            const float mn = fmaxf(m[r], lm);
            const float al = __expf(m[r] - mn);
            float ps = 0.f;
#pragma unroll
            for (int nf = 0; nf < 4; ++nf) {
                const float pe = __expf(sv[nf] - mn);
                p[nf][r] = pe;
                ps += pe;
            }
            ps += __shfl_xor(ps, 1);
            ps += __shfl_xor(ps, 2);
            ps += __shfl_xor(ps, 4);
            ps += __shfl_xor(ps, 8);
            l[r] = l[r] * al + ps;
            m[r] = mn;
#pragma unroll
            for (int df = 0; df < 8; ++df) O[df][r] *= al;
        }
        // P -> per-wave LDS tile (bf16), then PV via MFMA
        const int pb = w * 16 * 72;
#pragma unroll
        for (int nf = 0; nf < 4; ++nf)
#pragma unroll
            for (int r = 0; r < 4; ++r) Ps[pb + (lg * 4 + r) * 72 + nf * 16 + lr] = f2b(p[nf][r]);
        bf16x8 pa[2];
#pragma unroll
        for (int ks2 = 0; ks2 < 2; ++ks2)
            pa[ks2] = *(const bf16x8*)&Ps[pb + lr * 72 + ks2 * 32 + lg * 8];
#pragma unroll
        for (int df = 0; df < 8; ++df)
#pragma unroll
            for (int ks2 = 0; ks2 < 2; ++ks2) {
                const bf16x8 bv = *(const bf16x8*)&Vt[(df * 16 + lr) * 72 + ks2 * 32 + lg * 8];
                O[df] = __builtin_amdgcn_mfma_f32_16x16x32_bf16(pa[ks2], bv, O[df], 0, 0, 0);
            }
    }
    // epilogue: /l, * gate, write bf16
    float invl[4];
#pragma unroll
    for (int r = 0; r < 4; ++r) invl[r] = 1.f / l[r];
#pragma unroll
    for (int df = 0; df < 8; ++df)
#pragma unroll
        for (int r = 0; r < 4; ++r) {
            const int qq = b * SL + q0 + w * 16 + lg * 4 + r;
            const int col = h * DVAL + df * 16 + lr;
            const float o = O[df][r] * invl[r];
            const float g = b2f(gateb[qq * (NHEADS * DVAL) + col]);
            outg[qq * (NHEADS * DVAL) + col] = f2b(o * g);
        }
}

extern "C" void kernel_launch(void* const* d_in, const int* in_sizes, int n_in, void* d_out,
                              int out_size, void* d_ws, size_t ws_size, hipStream_t stream) {
    const float* hs = (const float*)d_in[0];
    const int* pos = (const int*)d_in[1];
    const float* Wq_down = (const float*)d_in[2];
    const float* q_norm_w = (const float*)d_in[3];
    const float* Wq_up = (const float*)d_in[4];
    const float* Wkv_down = (const float*)d_in[5];
    const float* kv_norm_w = (const float*)d_in[6];
    const float* Wkv_up = (const float*)d_in[7];
    const float* W_gate = (const float*)d_in[8];
    const float* W_out = (const float*)d_in[9];
    float* out = (float*)d_out;

    u16* p = (u16*)d_ws;
    u16* hs16 = p;      p += (size_t)TTOK * HIDN;            // 8.4M
    u16* wqd_t = p;     p += (size_t)QLRANK * HIDN;          // [1536][2048]
    u16* wqu_t = p;     p += (size_t)(NHEADS * QHEAD) * QLRANK;  // [3072][1536]
    u16* wkvd_t = p;    p += (size_t)576 * HIDN;             // [576][2048]
    u16* wkvu_t = p;    p += (size_t)(NHEADS * 256) * KVLRANK;  // [4096][512]
    u16* wg_t = p;      p += (size_t)HIDN * HIDN;            // [2048][2048]
    u16* wo_t = p;      p += (size_t)HIDN * (NHEADS * DVAL); // [2048][2048]
    u16* qdown = p;     p += (size_t)TTOK * QLRANK;
    u16* qbuf = p;      p += (size_t)TTOK * (NHEADS * QHEAD);
    u16* ckv = p;       p += (size_t)TTOK * 576;
    u16* kvn = p;       p += (size_t)TTOK * KVLRANK;
    u16* kvbuf = p;     p += (size_t)TTOK * (NHEADS * 256);
    u16* krb = p;       p += (size_t)TTOK * DROPE;
    u16* vTg = p;       p += (size_t)32 * 128 * SL;
    u16* gateb = p;     p += (size_t)TTOK * (NHEADS * DVAL);
    u16* outg = p;      p += (size_t)TTOK * (NHEADS * DVAL);

    const dim3 blk(256);

    // --- precast ---
    cast_k<<<dim3(2048), blk, 0, stream>>>(hs, hs16, TTOK * HIDN / 4);
    tcast_k<<<dim3(QLRANK / 64, HIDN / 64), blk, 0, stream>>>(Wq_down, wqd_t, HIDN, QLRANK);
    tcast_k<<<dim3((NHEADS * QHEAD) / 64, QLRANK / 64), blk, 0, stream>>>(Wq_up, wqu_t, QLRANK,
                                                                          NHEADS * QHEAD);
    tcast_k<<<dim3(576 / 64, HIDN / 64), blk, 0, stream>>>(Wkv_down, wkvd_t, HIDN, 576);
    tcast_k<<<dim3((NHEADS * 256) / 64, KVLRANK / 64), blk, 0, stream>>>(Wkv_up, wkvu_t, KVLRANK,
                                                                         NHEADS * 256);
    tcast_k<<<dim3(HIDN / 64, HIDN / 64), blk, 0, stream>>>(W_gate, wg_t, HIDN, HIDN);
    tcast_k<<<dim3(HIDN / 64, (NHEADS * DVAL) / 64), blk, 0, stream>>>(W_out, wo_t, NHEADS * DVAL,
                                                                       HIDN);

    // --- GEMM chain ---
    gemm_bf16_k<0, 0><<<dim3(QLRANK / 128, TTOK / 128), blk, 0, stream>>>(hs16, wqd_t, qdown, TTOK,
                                                                          QLRANK, HIDN);
    rmsnorm_k<<<dim3(TTOK), blk, 0, stream>>>(qdown, qdown, q_norm_w, QLRANK, QLRANK, QLRANK);
    gemm_bf16_k<0, 0><<<dim3((NHEADS * QHEAD) / 128, TTOK / 128), blk, 0, stream>>>(
        qdown, wqu_t, qbuf, TTOK, NHEADS * QHEAD, QLRANK);
    gemm_bf16_k<0, 0><<<dim3((576 + 127) / 128, TTOK / 128), blk, 0, stream>>>(hs16, wkvd_t, ckv,
                                                                               TTOK, 576, HIDN);
    rmsnorm_k<<<dim3(TTOK), blk, 0, stream>>>(ckv, kvn, kv_norm_w, 576, KVLRANK, KVLRANK);
    gemm_bf16_k<0, 0><<<dim3((NHEADS * 256) / 128, TTOK / 128), blk, 0, stream>>>(
        kvn, wkvu_t, kvbuf, TTOK, NHEADS * 256, KVLRANK);
    rope_k<<<dim3(TTOK / 2), dim3(64), 0, stream>>>(qbuf, ckv, krb, pos);
    vtrans_k<<<dim3(SL / 64, 2, 32), blk, 0, stream>>>(kvbuf, vTg);
    gemm_bf16_k<1, 0><<<dim3((NHEADS * DVAL) / 128, TTOK / 128), blk, 0, stream>>>(
        hs16, wg_t, gateb, TTOK, NHEADS * DVAL, HIDN);

    // --- attention (gate fused) ---
    mla_attn_k<<<dim3(SL / 64, 32), blk, 0, stream>>>(qbuf, kvbuf, krb, vTg, gateb, outg);

    // --- output projection (f32 out) ---
    gemm_bf16_k<0, 1><<<dim3(HIDN / 128, TTOK / 128), blk, 0, stream>>>(outg, wo_t, out, TTOK, HIDN,
                                                                        NHEADS * DVAL);
}

// Round 4
// 649.948 us; speedup vs baseline: 8.6726x; 1.2534x over previous
//
#include <hip/hip_runtime.h>
#include <math.h>

#define BT 2
#define SL 2048
#define HIDN 2048
#define NHEADS 16
#define DNOPE 128
#define DROPE 64
#define DVAL 128
#define QHEAD 192
#define QLRANK 1536
#define KVLRANK 512
#define TTOK (BT * SL)

typedef unsigned short u16;
typedef u16 u16x4 __attribute__((ext_vector_type(4)));
typedef short bf16x8 __attribute__((ext_vector_type(8)));
typedef float f32x4 __attribute__((ext_vector_type(4)));

__device__ __forceinline__ u16 f2b(float f) {
    union { float f; unsigned u; } v; v.f = f;
    unsigned r = v.u + 0x7FFFu + ((v.u >> 16) & 1u);
    return (u16)(r >> 16);
}
__device__ __forceinline__ float b2f(u16 h) {
    union { unsigned u; float f; } v; v.u = ((unsigned)h) << 16;
    return v.f;
}

// async global->LDS, 16B per lane. dest = wave-uniform base; HW adds lane*16.
__device__ __forceinline__ void gl2lds16(const u16* g, u16* l) {
    __builtin_amdgcn_global_load_lds((const __attribute__((address_space(1))) unsigned int*)g,
                                     (__attribute__((address_space(3))) unsigned int*)l, 16, 0, 0);
}

// ---------------- cast f32 -> bf16 (vectorized) ----------------
__global__ __launch_bounds__(256) void cast_k(const float* __restrict__ in, u16* __restrict__ out,
                                              int n4) {
    int i = blockIdx.x * 256 + threadIdx.x;
    const int stride = gridDim.x * 256;
    for (; i < n4; i += stride) {
        const float4 v = ((const float4*)in)[i];
        u16x4 u;
        u.x = f2b(v.x); u.y = f2b(v.y); u.z = f2b(v.z); u.w = f2b(v.w);
        ((u16x4*)out)[i] = u;
    }
}

// ---------------- transpose-cast: in [R][C] f32 -> out [C][R] bf16, 64x64 LDS tiles ----------------
__global__ __launch_bounds__(256) void tcast_k(const float* __restrict__ in, u16* __restrict__ out,
                                               int R, int C) {
    __shared__ u16 tile[64][72];
    const int c0 = blockIdx.x * 64, r0 = blockIdx.y * 64;
    const int t = threadIdx.x;
    const int tr = t >> 4, tc4 = (t & 15) * 4;
#pragma unroll
    for (int i = 0; i < 4; ++i) {
        const int r = tr + i * 16;
        const float4 v = *(const float4*)&in[(r0 + r) * C + c0 + tc4];
        u16x4 u;
        u.x = f2b(v.x); u.y = f2b(v.y); u.z = f2b(v.z); u.w = f2b(v.w);
        *(u16x4*)&tile[r][tc4] = u;
    }
    __syncthreads();
#pragma unroll
    for (int i = 0; i < 4; ++i) {
        const int rr = tr + i * 16;  // output row = input col
        u16x4 u;
        u.x = tile[tc4 + 0][rr];
        u.y = tile[tc4 + 1][rr];
        u.z = tile[tc4 + 2][rr];
        u.w = tile[tc4 + 3][rr];
        *(u16x4*)&out[(c0 + rr) * R + r0 + tc4] = u;
    }
}

// ---------------- V transpose: kvbuf [tok][h*256+128+d] bf16 -> vT [bh][128][2048] bf16 ----------------
__global__ __launch_bounds__(256) void vtrans_k(const u16* __restrict__ kvbuf,
                                                u16* __restrict__ vT) {
    __shared__ u16 tile[64][72];
    const int bh = blockIdx.z;
    const int b = bh >> 4, h = bh & 15;
    const int s0 = blockIdx.x * 64, d0 = blockIdx.y * 64;
    const int t = threadIdx.x;
    const int tr = t >> 4, tc4 = (t & 15) * 4;
#pragma unroll
    for (int i = 0; i < 4; ++i) {
        const int s = tr + i * 16;
        *(u16x4*)&tile[s][tc4] =
            *(const u16x4*)&kvbuf[(b * SL + s0 + s) * 4096 + h * 256 + 128 + d0 + tc4];
    }
    __syncthreads();
#pragma unroll
    for (int i = 0; i < 4; ++i) {
        const int dd = tr + i * 16;
        u16x4 u;
        u.x = tile[tc4 + 0][dd];
        u.y = tile[tc4 + 1][dd];
        u.z = tile[tc4 + 2][dd];
        u.w = tile[tc4 + 3][dd];
        *(u16x4*)&vT[(bh * 128 + d0 + dd) * SL + s0 + tc4] = u;
    }
}

// ---------------- bf16 MFMA GEMM: C[M,N] = A[M,K] @ Bt[N,K]^T ----------------
// 128x128 tile, BK=64, 256 threads (4 waves 2x2), 4x4 16x16x32 frags per wave.
// global_load_lds staging, linear LDS [128][64] with XOR-swizzle (pre-swizzled source).
template <int EPI, int OUTF>  // EPI: 0 none, 1 sigmoid; OUTF: 0 bf16 out, 1 f32 out
__global__ __launch_bounds__(256) void gemm_bf16_k(const u16* __restrict__ A,
                                                   const u16* __restrict__ Bt,
                                                   void* __restrict__ Cv, int M, int N, int K) {
    __shared__ u16 As[128 * 64];
    __shared__ u16 Bs[128 * 64];
    const int t = threadIdx.x;
    const int bn = blockIdx.x * 128, bm = blockIdx.y * 128;
    const int w = t >> 6, lane = t & 63;
    const int wr = (w >> 1) * 64, wc = (w & 1) * 64;
    const int lr = lane & 15, lg = lane >> 4;

    // staging: per wave-instr j (4 each for A,B): rows w*32+j*8 .. +7, 8 lanes/row, 16B/lane.
    // source col pre-swizzled so linear LDS write + XOR'd read = conflict-free (rule #21).
    const int srow = w * 32 + (lane >> 3);
    const int scol = ((lane & 7) ^ ((lane >> 3) & 7)) * 8;
    const u16* Ag = A + (size_t)(bm + srow) * K + scol;
    const u16* Bg = Bt + (size_t)(bn + srow) * K + scol;
    u16* Asl = As + w * 2048;  // wave-uniform base (+ j*512)
    u16* Bsl = Bs + w * 2048;

    f32x4 acc[4][4];
#pragma unroll
    for (int i = 0; i < 4; ++i)
#pragma unroll
        for (int j = 0; j < 4; ++j) acc[i][j] = 0.f;

    for (int k0 = 0; k0 < K; k0 += 64) {
        __syncthreads();  // previous iteration's LDS reads done
#pragma unroll
        for (int j = 0; j < 4; ++j) gl2lds16(Ag + (size_t)(j * 8) * K + k0, Asl + j * 512);
#pragma unroll
        for (int j = 0; j < 4; ++j) gl2lds16(Bg + (size_t)(j * 8) * K + k0, Bsl + j * 512);
        __syncthreads();  // compiler drains vmcnt before barrier
#pragma unroll
        for (int kk = 0; kk < 2; ++kk) {
            bf16x8 af[4], bfr[4];
#pragma unroll
            for (int mi = 0; mi < 4; ++mi) {
                const int row = wr + mi * 16 + lr;
                const int idx = (row * 64 + kk * 32 + lg * 8) ^ ((row & 7) << 3);
                af[mi] = *(const bf16x8*)&As[idx];
            }
#pragma unroll
            for (int ni = 0; ni < 4; ++ni) {
                const int row = wc + ni * 16 + lr;
                const int idx = (row * 64 + kk * 32 + lg * 8) ^ ((row & 7) << 3);
                bfr[ni] = *(const bf16x8*)&Bs[idx];
            }
#pragma unroll
            for (int mi = 0; mi < 4; ++mi)
#pragma unroll
                for (int ni = 0; ni < 4; ++ni)
                    acc[mi][ni] = __builtin_amdgcn_mfma_f32_16x16x32_bf16(af[mi], bfr[ni],
                                                                          acc[mi][ni], 0, 0, 0);
        }
    }
#pragma unroll
    for (int mi = 0; mi < 4; ++mi)
#pragma unroll
        for (int ni = 0; ni < 4; ++ni)
#pragma unroll
            for (int r = 0; r < 4; ++r) {
                const int row = bm + wr + mi * 16 + lg * 4 + r;
                const int col = bn + wc + ni * 16 + lr;
                float v = acc[mi][ni][r];
                if (EPI == 1) v = 1.f / (1.f + __expf(-v));
                if (col < N) {
                    if (OUTF)
                        ((float*)Cv)[(size_t)row * N + col] = v;
                    else
                        ((u16*)Cv)[(size_t)row * N + col] = f2b(v);
                }
            }
}

// ---------------- RMS norm (bf16 in/out, f32 weight) ----------------
__global__ __launch_bounds__(256) void rmsnorm_k(const u16* __restrict__ in, u16* __restrict__ out,
                                                 const float* __restrict__ w, int is, int os,
                                                 int n) {
    const int row = blockIdx.x;
    const int t = threadIdx.x;
    const u16* x = in + row * is;
    u16* y = out + row * os;
    float ss = 0.f;
    for (int d = t * 4; d < n; d += 1024) {
        const u16x4 u = *(const u16x4*)&x[d];
        const float a = b2f(u.x), b = b2f(u.y), c = b2f(u.z), e = b2f(u.w);
        ss += a * a + b * b + c * c + e * e;
    }
    ss += __shfl_down(ss, 32);
    ss += __shfl_down(ss, 16);
    ss += __shfl_down(ss, 8);
    ss += __shfl_down(ss, 4);
    ss += __shfl_down(ss, 2);
    ss += __shfl_down(ss, 1);
    __shared__ float red[5];
    if ((t & 63) == 0) red[t >> 6] = ss;
    __syncthreads();
    if (t == 0) red[4] = rsqrtf((red[0] + red[1] + red[2] + red[3]) / (float)n + 1e-6f);
    __syncthreads();
    const float sc = red[4];
    for (int d = t * 4; d < n; d += 1024) {
        const u16x4 u = *(const u16x4*)&x[d];
        const float4 wv = *(const float4*)&w[d];
        u16x4 o;
        o.x = f2b(b2f(u.x) * sc * (1.f + wv.x));
        o.y = f2b(b2f(u.y) * sc * (1.f + wv.y));
        o.z = f2b(b2f(u.z) * sc * (1.f + wv.z));
        o.w = f2b(b2f(u.w) * sc * (1.f + wv.w));
        *(u16x4*)&y[d] = o;
    }
}

// ---------------- RoPE (bf16): q in-place, ckv rope slice -> kr ----------------
__global__ __launch_bounds__(64) void rope_k(u16* __restrict__ q, const u16* __restrict__ ckv,
                                             u16* __restrict__ kr, const int* __restrict__ pos_ids) {
    const int tok = blockIdx.x * 2 + (threadIdx.x >> 5);
    const int j = threadIdx.x & 31;
    const int s = tok & (SL - 1);
    const float pos = (float)pos_ids[s];
    const float inv = 1.f / powf(10000.f, (float)(2 * j) / 64.f);
    const float f = pos * inv;
    const float c = cosf(f), sn = sinf(f);
    const u16* kc = ckv + tok * 576 + 512;
    const float ke = b2f(kc[2 * j]), ko = b2f(kc[2 * j + 1]);
    kr[tok * 64 + j] = f2b(ke * c - ko * sn);
    kr[tok * 64 + 32 + j] = f2b(ko * c + ke * sn);
#pragma unroll
    for (int h = 0; h < NHEADS; ++h) {
        u16* qb = q + tok * (NHEADS * QHEAD) + h * QHEAD + DNOPE;
        const float qe = b2f(qb[2 * j]), qo = b2f(qb[2 * j + 1]);
        qb[j] = f2b(qe * c - qo * sn);
        qb[32 + j] = f2b(qo * c + qe * sn);
    }
}

// ---------------- MFMA flash attention, gate fused ----------------
// block = 256 (4 waves); q-tile 128 (32 rows/wave via 2 m-frags); key tiles of 64.
__global__ __launch_bounds__(256, 2) void mla_attn_k(const u16* __restrict__ qbuf,
                                                     const u16* __restrict__ kvbuf,
                                                     const u16* __restrict__ kr,
                                                     const u16* __restrict__ vT,
                                                     const u16* __restrict__ gateb,
                                                     u16* __restrict__ outg) {
    __shared__ u16 Ks[64 * 200];
    __shared__ u16 Vt[128 * 72];
    __shared__ u16 Ps[4 * 32 * 72];
    const int bh = blockIdx.y;
    const int b = bh >> 4, h = bh & 15;
    const int q0 = blockIdx.x * 128;
    const int t = threadIdx.x, w = t >> 6, lane = t & 63;
    const int lr = lane & 15, lg = lane >> 4;
    const float scale = 0.07216878364870322f;  // 1/sqrt(192)

    // Q fragments in registers: wave w owns q rows q0+w*32 .. +31 (2 frags of 16)
    bf16x8 aq[2][6];
#pragma unroll
    for (int mi = 0; mi < 2; ++mi) {
        const int qrow = b * SL + q0 + w * 32 + mi * 16 + lr;
#pragma unroll
        for (int ks = 0; ks < 6; ++ks)
            aq[mi][ks] =
                *(const bf16x8*)&qbuf[qrow * (NHEADS * QHEAD) + h * QHEAD + ks * 32 + lg * 8];
    }

    f32x4 O[2][8];
#pragma unroll
    for (int mi = 0; mi < 2; ++mi)
#pragma unroll
        for (int df = 0; df < 8; ++df) O[mi][df] = 0.f;
    float m[2][4], l[2][4];
#pragma unroll
    for (int mi = 0; mi < 2; ++mi)
#pragma unroll
        for (int r = 0; r < 4; ++r) {
            m[mi][r] = -INFINITY;
            l[mi][r] = 0.f;
        }

    for (int k0 = 0; k0 < SL; k0 += 64) {
        __syncthreads();  // prior iteration's reads done before overwrite
        // K tile: 64 rows x 192 cols = 3072 u16x4 chunks
        for (int i = t; i < 3072; i += 256) {
            const int row = i / 48, c4 = (i % 48) * 4;
            const int tok = b * SL + k0 + row;
            u16x4 v;
            if (c4 < 128)
                v = *(const u16x4*)&kvbuf[tok * 4096 + h * 256 + c4];
            else
                v = *(const u16x4*)&kr[tok * 64 + (c4 - 128)];
            *(u16x4*)&Ks[row * 200 + c4] = v;
        }
        for (int i = t; i < 2048; i += 256) {
            const int row = i >> 4, c4 = (i & 15) * 4;
            *(u16x4*)&Vt[row * 72 + c4] = *(const u16x4*)&vT[(bh * 128 + row) * SL + k0 + c4];
        }
        __syncthreads();

        // S = Q K^T  (2 m-frags x 4 n-frags, 6 k-steps over d=192; each Ks read feeds 2 MFMAs)
        f32x4 s[2][4];
#pragma unroll
        for (int mi = 0; mi < 2; ++mi)
#pragma unroll
            for (int nf = 0; nf < 4; ++nf) s[mi][nf] = 0.f;
#pragma unroll
        for (int ks = 0; ks < 6; ++ks) {
#pragma unroll
            for (int nf = 0; nf < 4; ++nf) {
                const bf16x8 bk = *(const bf16x8*)&Ks[(nf * 16 + lr) * 200 + ks * 32 + lg * 8];
                s[0][nf] = __builtin_amdgcn_mfma_f32_16x16x32_bf16(aq[0][ks], bk, s[0][nf], 0, 0, 0);
                s[1][nf] = __builtin_amdgcn_mfma_f32_16x16x32_bf16(aq[1][ks], bk, s[1][nf], 0, 0, 0);
            }
        }
        // online softmax (rows: lg*4+r; cols: lr + 16*nf), per m-frag
#pragma unroll
        for (int mi = 0; mi < 2; ++mi) {
            float p[4][4];
#pragma unroll
            for (int r = 0; r < 4; ++r) {
                float sv[4];
                float lm = -INFINITY;
#pragma unroll
                for (int nf = 0; nf < 4; ++nf) {
                    sv[nf] = s[mi][nf][r] * scale;
                    lm = fmaxf(lm, sv[nf]);
                }
                lm = fmaxf(lm, __shfl_xor(lm, 1));
                lm = fmaxf(lm, __shfl_xor(lm, 2));
                lm = fmaxf(lm, __shfl_xor(lm, 4));
                lm = fmaxf(lm, __shfl_xor(lm, 8));
                const float mn = fmaxf(m[mi][r], lm);
                const float al = __expf(m[mi][r] - mn);
                float ps = 0.f;
#pragma unroll
                for (int nf = 0; nf < 4; ++nf) {
                    const float pe = __expf(sv[nf] - mn);
                    p[nf][r] = pe;
                    ps += pe;
                }
                ps += __shfl_xor(ps, 1);
                ps += __shfl_xor(ps, 2);
                ps += __shfl_xor(ps, 4);
                ps += __shfl_xor(ps, 8);
                l[mi][r] = l[mi][r] * al + ps;
                m[mi][r] = mn;
#pragma unroll
                for (int df = 0; df < 8; ++df) O[mi][df][r] *= al;
            }
            const int pb = w * 32 * 72 + mi * 16 * 72;
#pragma unroll
            for (int nf = 0; nf < 4; ++nf)
#pragma unroll
                for (int r = 0; r < 4; ++r)
                    Ps[pb + (lg * 4 + r) * 72 + nf * 16 + lr] = f2b(p[nf][r]);
        }
        // PV via MFMA; each Vt read feeds 2 MFMAs
        bf16x8 pa[2][2];
#pragma unroll
        for (int mi = 0; mi < 2; ++mi)
#pragma unroll
            for (int ks2 = 0; ks2 < 2; ++ks2)
                pa[mi][ks2] =
                    *(const bf16x8*)&Ps[w * 32 * 72 + (mi * 16 + lr) * 72 + ks2 * 32 + lg * 8];
#pragma unroll
        for (int df = 0; df < 8; ++df)
#pragma unroll
            for (int ks2 = 0; ks2 < 2; ++ks2) {
                const bf16x8 bv = *(const bf16x8*)&Vt[(df * 16 + lr) * 72 + ks2 * 32 + lg * 8];
                O[0][df] = __builtin_amdgcn_mfma_f32_16x16x32_bf16(pa[0][ks2], bv, O[0][df], 0, 0, 0);
                O[1][df] = __builtin_amdgcn_mfma_f32_16x16x32_bf16(pa[1][ks2], bv, O[1][df], 0, 0, 0);
            }
    }
    // epilogue: /l, * gate, write bf16
#pragma unroll
    for (int mi = 0; mi < 2; ++mi) {
        float invl[4];
#pragma unroll
        for (int r = 0; r < 4; ++r) invl[r] = 1.f / l[mi][r];
#pragma unroll
        for (int df = 0; df < 8; ++df)
#pragma unroll
            for (int r = 0; r < 4; ++r) {
                const int qq = b * SL + q0 + w * 32 + mi * 16 + lg * 4 + r;
                const int col = h * DVAL + df * 16 + lr;
                const float o = O[mi][df][r] * invl[r];
                const float g = b2f(gateb[qq * (NHEADS * DVAL) + col]);
                outg[qq * (NHEADS * DVAL) + col] = f2b(o * g);
            }
    }
}

extern "C" void kernel_launch(void* const* d_in, const int* in_sizes, int n_in, void* d_out,
                              int out_size, void* d_ws, size_t ws_size, hipStream_t stream) {
    const float* hs = (const float*)d_in[0];
    const int* pos = (const int*)d_in[1];
    const float* Wq_down = (const float*)d_in[2];
    const float* q_norm_w = (const float*)d_in[3];
    const float* Wq_up = (const float*)d_in[4];
    const float* Wkv_down = (const float*)d_in[5];
    const float* kv_norm_w = (const float*)d_in[6];
    const float* Wkv_up = (const float*)d_in[7];
    const float* W_gate = (const float*)d_in[8];
    const float* W_out = (const float*)d_in[9];
    float* out = (float*)d_out;

    u16* p = (u16*)d_ws;
    u16* hs16 = p;      p += (size_t)TTOK * HIDN;
    u16* wqd_t = p;     p += (size_t)QLRANK * HIDN;
    u16* wqu_t = p;     p += (size_t)(NHEADS * QHEAD) * QLRANK;
    u16* wkvd_t = p;    p += (size_t)576 * HIDN;
    u16* wkvu_t = p;    p += (size_t)(NHEADS * 256) * KVLRANK;
    u16* wg_t = p;      p += (size_t)HIDN * HIDN;
    u16* wo_t = p;      p += (size_t)HIDN * (NHEADS * DVAL);
    u16* qdown = p;     p += (size_t)TTOK * QLRANK;
    u16* qbuf = p;      p += (size_t)TTOK * (NHEADS * QHEAD);
    u16* ckv = p;       p += (size_t)TTOK * 576;
    u16* kvn = p;       p += (size_t)TTOK * KVLRANK;
    u16* kvbuf = p;     p += (size_t)TTOK * (NHEADS * 256);
    u16* krb = p;       p += (size_t)TTOK * DROPE;
    u16* vTg = p;       p += (size_t)32 * 128 * SL;
    u16* gateb = p;     p += (size_t)TTOK * (NHEADS * DVAL);
    u16* outg = p;      p += (size_t)TTOK * (NHEADS * DVAL);

    const dim3 blk(256);

    // --- precast ---
    cast_k<<<dim3(2048), blk, 0, stream>>>(hs, hs16, TTOK * HIDN / 4);
    tcast_k<<<dim3(QLRANK / 64, HIDN / 64), blk, 0, stream>>>(Wq_down, wqd_t, HIDN, QLRANK);
    tcast_k<<<dim3((NHEADS * QHEAD) / 64, QLRANK / 64), blk, 0, stream>>>(Wq_up, wqu_t, QLRANK,
                                                                          NHEADS * QHEAD);
    tcast_k<<<dim3(576 / 64, HIDN / 64), blk, 0, stream>>>(Wkv_down, wkvd_t, HIDN, 576);
    tcast_k<<<dim3((NHEADS * 256) / 64, KVLRANK / 64), blk, 0, stream>>>(Wkv_up, wkvu_t, KVLRANK,
                                                                         NHEADS * 256);
    tcast_k<<<dim3(HIDN / 64, HIDN / 64), blk, 0, stream>>>(W_gate, wg_t, HIDN, HIDN);
    tcast_k<<<dim3(HIDN / 64, (NHEADS * DVAL) / 64), blk, 0, stream>>>(W_out, wo_t, NHEADS * DVAL,
                                                                       HIDN);

    // --- GEMM chain ---
    gemm_bf16_k<0, 0><<<dim3(QLRANK / 128, TTOK / 128), blk, 0, stream>>>(hs16, wqd_t, qdown, TTOK,
                                                                          QLRANK, HIDN);
    rmsnorm_k<<<dim3(TTOK), blk, 0, stream>>>(qdown, qdown, q_norm_w, QLRANK, QLRANK, QLRANK);
    gemm_bf16_k<0, 0><<<dim3((NHEADS * QHEAD) / 128, TTOK / 128), blk, 0, stream>>>(
        qdown, wqu_t, qbuf, TTOK, NHEADS * QHEAD, QLRANK);
    gemm_bf16_k<0, 0><<<dim3((576 + 127) / 128, TTOK / 128), blk, 0, stream>>>(hs16, wkvd_t, ckv,
                                                                               TTOK, 576, HIDN);
    rmsnorm_k<<<dim3(TTOK), blk, 0, stream>>>(ckv, kvn, kv_norm_w, 576, KVLRANK, KVLRANK);
    gemm_bf16_k<0, 0><<<dim3((NHEADS * 256) / 128, TTOK / 128), blk, 0, stream>>>(
        kvn, wkvu_t, kvbuf, TTOK, NHEADS * 256, KVLRANK);
    rope_k<<<dim3(TTOK / 2), dim3(64), 0, stream>>>(qbuf, ckv, krb, pos);
    vtrans_k<<<dim3(SL / 64, 2, 32), blk, 0, stream>>>(kvbuf, vTg);
    gemm_bf16_k<1, 0><<<dim3((NHEADS * DVAL) / 128, TTOK / 128), blk, 0, stream>>>(
        hs16, wg_t, gateb, TTOK, NHEADS * DVAL, HIDN);

    // --- attention (gate fused) ---
    mla_attn_k<<<dim3(SL / 128, 32), blk, 0, stream>>>(qbuf, kvbuf, krb, vTg, gateb, outg);

    // --- output projection (f32 out) ---
    gemm_bf16_k<0, 1><<<dim3(HIDN / 128, TTOK / 128), blk, 0, stream>>>(outg, wo_t, out, TTOK, HIDN,
                                                                        NHEADS * DVAL);
}